// Round 1
// baseline (395.618 us; speedup 1.0000x reference)
//
#include <hip/hip_runtime.h>

// Bilinear 4x upsample (depthwise conv_transpose2d, stride=4, 7x7 bilinear kernel).
// Input  x: [4, 256, 64, 64]  fp32
// Output o: [4, 256, 259, 259] fp32
// Each output (oy,ox) with oy=4*qy+py, ox=4*qx+px gets at most 2x2 taps:
//   row qy-1 weight 0.25*(3-py), row qy weight 0.25*(py+1)  (same in x).
// Weights are the exact separable bilinear taps [.25,.5,.75,1,.75,.5,.25].

#define IH 64
#define IW 64
#define OH 259
#define OW 259

__global__ __launch_bounds__(256) void upsample_bilinear4x_kernel(
    const float* __restrict__ x, float* __restrict__ out, int total)
{
    int idx = blockIdx.x * 256 + threadIdx.x;
    if (idx >= total) return;

    unsigned u   = (unsigned)idx;
    unsigned ox  = u % OW;          // compile-time const divisor -> magic mul
    unsigned r   = u / OW;
    unsigned oy  = r % OH;
    unsigned nc  = r / OH;

    int qy = (int)(oy >> 2), py = (int)(oy & 3);
    int qx = (int)(ox >> 2), px = (int)(ox & 3);

    // 1-D bilinear weights for the two taps (lo = q-1, hi = q)
    float wyl = 0.25f * (float)(3 - py);
    float wyh = 0.25f * (float)(py + 1);
    float wxl = 0.25f * (float)(3 - px);
    float wxh = 0.25f * (float)(px + 1);

    int iyl = qy - 1; if (iyl < 0)      { iyl = 0;      wyl = 0.0f; }
    int iyh = qy;     if (iyh > IH - 1) { iyh = IH - 1; wyh = 0.0f; }
    int ixl = qx - 1; if (ixl < 0)      { ixl = 0;      wxl = 0.0f; }
    int ixh = qx;     if (ixh > IW - 1) { ixh = IW - 1; wxh = 0.0f; }

    const float* __restrict__ xp = x + (size_t)nc * (IH * IW);

    float x00 = xp[iyl * IW + ixl];
    float x01 = xp[iyl * IW + ixh];
    float x10 = xp[iyh * IW + ixl];
    float x11 = xp[iyh * IW + ixh];

    float vl = wyl * x00 + wyh * x10;   // column ixl combined vertically
    float vh = wyl * x01 + wyh * x11;   // column ixh combined vertically

    out[idx] = wxl * vl + wxh * vh;
}

extern "C" void kernel_launch(void* const* d_in, const int* in_sizes, int n_in,
                              void* d_out, int out_size, void* d_ws, size_t ws_size,
                              hipStream_t stream)
{
    const float* x = (const float*)d_in[0];
    // d_in[1] (weight) is the fixed bilinear kernel; taps are hardcoded exactly.
    float* out = (float*)d_out;

    int total = out_size;               // 4*256*259*259 = 68,690,944
    int block = 256;
    int grid  = (total + block - 1) / block;
    upsample_bilinear4x_kernel<<<grid, block, 0, stream>>>(x, out, total);
}

// Round 2
// 314.423 us; speedup vs baseline: 1.2582x; 1.2582x over previous
//
#include <hip/hip_runtime.h>

// Bilinear 4x upsample (depthwise conv_transpose2d, stride=4, 7x7 bilinear taps).
// in  x:   [4,256,64,64]  fp32   (nc = 0..1023)
// out:     [4,256,259,259] fp32
// out[oy=4q+p] taps input rows q-1 (w=.25*(3-p)) and q (w=.25*(p+1)); same in x.
//
// Structure: block = (nc, qy), 4 waves = 4 output rows (py=0..3) sharing input
// rows qy-1, qy. Lane l loads column l of both rows (coalesced), forms the
// vertical combo v0, fetches neighbor combos via shuffle, and writes 4 outputs
// as ONE 16B-aligned float4. Row starts are not 16B-aligned (OW=259), so each
// row = s leading scalars (lane 0) + 64 aligned float4 + (3-s) trailing (lane 63).

#define IH 64
#define IW 64
#define OH 259
#define OW 259
#define NC 1024

__global__ __launch_bounds__(256) void upsample4x_rows(
    const float* __restrict__ x, float* __restrict__ out)
{
    const int qy   = blockIdx.x;         // 0..64
    const int nc   = blockIdx.y;         // 0..1023
    const int py   = threadIdx.x >> 6;   // wave id = output sub-row
    const int lane = threadIdx.x & 63;

    const int oy = 4 * qy + py;
    if (oy >= OH) return;                // only qy==64, py==3

    // vertical taps (rows qy-1, qy), zero weight when out of range
    float wyl = 0.25f * (float)(3 - py);
    float wyh = 0.25f * (float)(py + 1);
    int iyl = qy - 1;
    int iyh = qy;
    if (iyl < 0)      { iyl = 0;      wyl = 0.0f; }
    if (iyh > IH - 1) { iyh = IH - 1; wyh = 0.0f; }

    const float* __restrict__ xp = x + (size_t)nc * (IH * IW);
    float xl = xp[iyl * IW + lane];      // coalesced 256B per wave
    float xh = xp[iyh * IW + lane];
    float v0 = wyl * xl + wyh * xh;      // vertical combo at column `lane`

    float vm1 = __shfl_up(v0, 1);        // column lane-1
    float vp1 = __shfl_down(v0, 1);      // column lane+1
    if (lane == 0)  vm1 = 0.0f;          // column -1  -> dropped tap
    if (lane == 63) vp1 = 0.0f;          // column 64  -> dropped tap

    const size_t row_off = (size_t)nc * (OH * OW) + (size_t)oy * OW;
    const int s = (int)((4 - (row_off & 3)) & 3);  // floats until 16B boundary

    // aligned region: ox = s + 4*lane + j, j=0..3; q = lane + ((s+j)>>2)
    float e0, e1, e2, e3;
    {
        float e[4];
#pragma unroll
        for (int j = 0; j < 4; ++j) {
            int sj = s + j;
            int c  = sj >> 2;            // wave-uniform 0/1
            int px = sj & 3;             // wave-uniform
            float wl = 0.25f * (float)(3 - px);
            float wh = 0.25f * (float)(px + 1);
            float lo = c ? v0  : vm1;    // column q-1
            float hi = c ? vp1 : v0;     // column q
            e[j] = wl * lo + wh * hi;
        }
        e0 = e[0]; e1 = e[1]; e2 = e[2]; e3 = e[3];
    }
    float4* dst = (float4*)(out + row_off + s);
    dst[lane] = make_float4(e0, e1, e2, e3);

    // leading ox = 0..s-1: q=0, taps col -1 (dropped) + col 0 -> 0.25*(ox+1)*v(0)
    if (lane == 0) {
        for (int ox = 0; ox < s; ++ox)
            out[row_off + ox] = 0.25f * (float)(ox + 1) * v0;
    }
    // trailing ox = s+256..258: q=64, taps col 63 + col 64 (dropped)
    //   -> 0.25*(3-(ox&3)) * v(63); v(63) is lane 63's v0
    if (lane == 63) {
        for (int ox = s + 256; ox < OW; ++ox)
            out[row_off + ox] = 0.25f * (float)(3 - (ox & 3)) * v0;
    }
}

extern "C" void kernel_launch(void* const* d_in, const int* in_sizes, int n_in,
                              void* d_out, int out_size, void* d_ws, size_t ws_size,
                              hipStream_t stream)
{
    const float* x = (const float*)d_in[0];
    // d_in[1] (weight) is the fixed bilinear kernel; taps are hardcoded exactly.
    float* out = (float*)d_out;

    dim3 grid(65, NC);   // qy groups x (batch*channels)
    dim3 block(256);     // 4 waves = 4 output rows
    upsample4x_rows<<<grid, block, 0, stream>>>(x, out);
}

// Round 3
// 310.291 us; speedup vs baseline: 1.2750x; 1.0133x over previous
//
#include <hip/hip_runtime.h>

// Bilinear 4x upsample (depthwise conv_transpose2d, stride=4, 7x7 bilinear taps).
// in  x: [4,256,64,64] fp32 ; out: [4,256,259,259] fp32
// out row oy=4q+py taps input rows q-1 (w=.25*(3-py)) and q (w=.25*(py+1));
// separable, same weights in x.
//
// R3 structure: one WAVE owns (nc, strip of 8 q-values) and loops q with a
// rolling register pair (xl=row q-1, xh=row q) + prefetch of row q+1.
// Per iteration: 1 coalesced 256B load, 2 shuffles, 4 output rows, each
// written as 64 aligned float4 (+ lane0/lane63 scalar tails for the
// misaligned row start/end; OW=259 so each row = s + 256 + (3-s) floats).
// Horizontal weights/selects depend only on (nc+3*py)&3 -> hoisted.

#define IH 64
#define IW 64
#define OH 259
#define OW 259
#define OROW 67081  // OH*OW

__global__ __launch_bounds__(256) void upsample4x_strip(
    const float* __restrict__ x, float* __restrict__ out)
{
    const int wv   = threadIdx.x >> 6;
    const int lane = threadIdx.x & 63;
    const int g    = blockIdx.x * 4 + wv;   // global wave id, 0..8191
    const int strip = g & 7;                // 0..7
    const int nc    = g >> 3;               // 0..1023

    const int q0 = strip * 8;
    const int q1 = (strip == 7) ? 65 : q0 + 8;  // strip 7 also handles q=64

    const float* __restrict__ xp = x + (size_t)nc * (IH * IW);
    const size_t out_base = (size_t)nc * OROW;

    // --- hoisted horizontal constants (per py) ---
    // row_off = nc*67081 + oy*259 ≡ nc + 3*py (mod 4)  (q drops out)
    float wl_t[4][4], wh_t[4][4];
    int   c_t[4][4];
    int   s_t[4];
#pragma unroll
    for (int py = 0; py < 4; ++py) {
        int s = (4 - ((nc + 3 * py) & 3)) & 3;
        s_t[py] = s;
#pragma unroll
        for (int j = 0; j < 4; ++j) {
            int sj = s + j;                 // 0..6
            c_t[py][j]  = sj >> 2;          // 0: taps (vm1,v0)  1: taps (v0,vp1)
            int px      = sj & 3;
            wl_t[py][j] = 0.25f * (float)(3 - px);
            wh_t[py][j] = 0.25f * (float)(px + 1);
        }
    }

    // --- rolling input rows (register-resident) ---
    float xl = (q0 == 0) ? 0.0f : xp[(q0 - 1) * IW + lane];  // row q0-1 (0 => tap dropped)
    float xh = xp[q0 * IW + lane];                            // row q0 (q0 <= 56 always valid)
    float xlm = __shfl_up(xl, 1);   if (lane == 0)  xlm = 0.0f;
    float xlp = __shfl_down(xl, 1); if (lane == 63) xlp = 0.0f;
    float xhm = __shfl_up(xh, 1);   if (lane == 0)  xhm = 0.0f;
    float xhp = __shfl_down(xh, 1); if (lane == 63) xhp = 0.0f;

    for (int q = q0; q < q1; ++q) {
        // prefetch next row (row q+1); q=64 gets xh=0 => hi tap dropped
        int qn = q + 1;
        float xn = 0.0f;
        if (qn < q1 && qn <= IH - 1) xn = xp[qn * IW + lane];

#pragma unroll
        for (int py = 0; py < 4; ++py) {
            int oy = 4 * q + py;
            if (oy < OH) {                  // false only for q==64, py==3
                float wyl = 0.25f * (float)(3 - py);
                float wyh = 0.25f * (float)(py + 1);
                float v0  = wyl * xl  + wyh * xh;    // vertical combo, col lane
                float vm1 = wyl * xlm + wyh * xhm;   // col lane-1 (0 at lane 0)
                float vp1 = wyl * xlp + wyh * xhp;   // col lane+1 (0 at lane 63)

                const int s = s_t[py];
                float e[4];
#pragma unroll
                for (int j = 0; j < 4; ++j) {
                    float lo = c_t[py][j] ? v0  : vm1;
                    float hi = c_t[py][j] ? vp1 : v0;
                    e[j] = wl_t[py][j] * lo + wh_t[py][j] * hi;
                }

                const size_t row = out_base + (size_t)oy * OW;
                float4* dst = (float4*)(out + row + s);
                dst[lane] = make_float4(e[0], e[1], e[2], e[3]);

                if (lane == 0)              // ox in [0,s): taps col -1(drop)+col 0
                    for (int ox = 0; ox < s; ++ox)
                        out[row + ox] = 0.25f * (float)(ox + 1) * v0;
                if (lane == 63)             // ox in [s+256,259): taps col 63+col 64(drop)
                    for (int ox = s + 256; ox < OW; ++ox)
                        out[row + ox] = 0.25f * (float)(3 - (ox & 3)) * v0;
            }
        }

        // roll rows: q-1 <- q, q <- q+1
        xl = xh; xlm = xhm; xlp = xhp;
        xh = xn;
        xhm = __shfl_up(xh, 1);   if (lane == 0)  xhm = 0.0f;
        xhp = __shfl_down(xh, 1); if (lane == 63) xhp = 0.0f;
    }
}

extern "C" void kernel_launch(void* const* d_in, const int* in_sizes, int n_in,
                              void* d_out, int out_size, void* d_ws, size_t ws_size,
                              hipStream_t stream)
{
    const float* x = (const float*)d_in[0];
    // d_in[1] (weight) is the fixed bilinear kernel; taps are hardcoded exactly.
    float* out = (float*)d_out;

    // 1024 nc * 8 strips = 8192 waves = 2048 blocks of 4 waves (32 waves/CU)
    upsample4x_strip<<<2048, 256, 0, stream>>>(x, out);
}